// Round 3
// baseline (240.947 us; speedup 1.0000x reference)
//
#include <hip/hip_runtime.h>
#include <math.h>

// ProbLoss: B=16, T=2048, D=512, C=20. Inputs (f32):
//   d_in[0] attn [B,T,1], d_in[1] mu [B,T,D], d_in[2] var [B,T,D],
//   d_in[3] mu_clip [B,T,D], d_in[4] text_feat [C,D], d_in[5] drop_mask [B,T]
// Output: 5 f32 scalars (total, distill, act_loss, bkg_loss, ortho).

#define BB 16
#define TT 2048
#define DD 512
#define CC 20
#define KEASY 40
#define KHARD 20
#define EPSF 1e-5f

typedef unsigned long long u64;

// ---- DPP wave-64 reductions / scans (VALU-only) ----
template <int CTRL>
__device__ __forceinline__ float dpp_mov(float x) {
  return __int_as_float(__builtin_amdgcn_update_dpp(
      0, __float_as_int(x), CTRL, 0xF, 0xF, true));  // bound_ctrl: 0-fill
}
template <int CTRL, int RM>
__device__ __forceinline__ unsigned dpp_movu(unsigned x) {
  return (unsigned)__builtin_amdgcn_update_dpp(0, (int)x, CTRL, RM, 0xF, true);
}
__device__ __forceinline__ float wsum63(float v) {  // total valid in lane 63
  v += dpp_mov<0x111>(v);
  v += dpp_mov<0x112>(v);
  v += dpp_mov<0x114>(v);
  v += dpp_mov<0x118>(v);
  v += dpp_mov<0x142>(v);
  v += dpp_mov<0x143>(v);
  return v;
}
__device__ __forceinline__ float wsum_bc(float v) {  // broadcast to all lanes
  return __int_as_float(__builtin_amdgcn_readlane(__float_as_int(wsum63(v)), 63));
}
__device__ __forceinline__ float wmax63(float v) {  // nonneg values; max in lane 63
  v = fmaxf(v, dpp_mov<0x111>(v));
  v = fmaxf(v, dpp_mov<0x112>(v));
  v = fmaxf(v, dpp_mov<0x114>(v));
  v = fmaxf(v, dpp_mov<0x118>(v));
  v = fmaxf(v, dpp_mov<0x142>(v));
  v = fmaxf(v, dpp_mov<0x143>(v));
  return v;
}
// Wave-64 inclusive prefix scan: row_bcast:15 needs row_mask=0xa and
// row_bcast:31 needs row_mask=0xc (canonical GCN scan).
__device__ __forceinline__ unsigned wscanu(unsigned v) {
  v += dpp_movu<0x111, 0xF>(v);
  v += dpp_movu<0x112, 0xF>(v);
  v += dpp_movu<0x114, 0xF>(v);
  v += dpp_movu<0x118, 0xF>(v);
  v += dpp_movu<0x142, 0xa>(v);  // row1 += lane15; row3 += lane47
  v += dpp_movu<0x143, 0xc>(v);  // rows 2,3 += lane31 (now sum[0..31])
  return v;
}

// k-th largest VALUE (with multiplicity) among the TT nonneg floats in LDS sbuf.
// Block-parallel radix select: 4 passes of 8-bit LDS histogram + wave0 DPP scan.
// IEEE nonneg floats order == uint order -> bit-exact threshold.
__device__ __forceinline__ float radix_kth(const float* sbuf, unsigned k,
                                           unsigned* s_hist, unsigned* s_state,
                                           int tid) {
#pragma unroll 1
  for (int round = 0; round < 4; ++round) {
    s_hist[tid] = 0;
    if (round == 0 && tid == 0) { s_state[0] = 0u; s_state[1] = k; }
    __syncthreads();
    const int shift = 24 - 8 * round;
    const unsigned mask_hi = (round == 0) ? 0u : (0xFFFFFFFFu << (shift + 8));
    const unsigned pref = s_state[0];
    const unsigned kk = s_state[1];
    // histogram, bin index DESCENDING in value; run-length pre-aggregation
    // caps same-bin LDS-atomic contention (score arrays are zero-heavy).
    unsigned curbin = 0xFFFFFFFFu, curc = 0;
    for (int i = tid; i < TT; i += 256) {
      const unsigned key = __float_as_uint(sbuf[i]);
      if ((key & mask_hi) == pref) {
        const unsigned bin = 255u - ((key >> shift) & 255u);
        if (bin == curbin) {
          curc++;
        } else {
          if (curc) atomicAdd(&s_hist[curbin], curc);
          curbin = bin;
          curc = 1;
        }
      }
    }
    if (curc) atomicAdd(&s_hist[curbin], curc);
    __syncthreads();
    if (tid < 64) {  // wave 0: pick the bin containing rank kk
      const uint4 h = *(const uint4*)(s_hist + 4 * tid);
      const unsigned s0 = h.x, s1 = s0 + h.y, s2 = s1 + h.z, s3 = s2 + h.w;
      const unsigned P = wscanu(s3);  // inclusive over lane totals
      const unsigned E = P - s3;      // exclusive
      const u64 bal = __ballot(P >= kk);
      const int L = (int)__ffsll(bal) - 1;  // first lane reaching kk
      if (tid == L) {
        unsigned binj, cb;
        if (E + s0 >= kk)      { binj = 0u; cb = E; }
        else if (E + s1 >= kk) { binj = 1u; cb = E + s0; }
        else if (E + s2 >= kk) { binj = 2u; cb = E + s1; }
        else                   { binj = 3u; cb = E + s2; }
        const unsigned digit = 255u - (4u * (unsigned)tid + binj);
        s_state[0] = pref | (digit << shift);
        s_state[1] = kk - cb;
      }
    }
    __syncthreads();
  }
  return __uint_as_float(s_state[0]);
}

// =======================================================================
// k1: blocks [0,64) = selection+slog; blocks [64,2112) = distill.
// __launch_bounds__(256,2): cap 256 VGPR. Distill needs ~90 live regs for
// the 16-loads-in-flight batch; the old (256,1)->VGPR=24 build broke the
// prefetch pipeline (2 KB in flight/wave -> latency-bound at 2 TB/s).
// =======================================================================
__global__ __launch_bounds__(256, 2) void k_main1(const float* __restrict__ attn,
                                                  const float* __restrict__ drop,
                                                  const float* __restrict__ mu,
                                                  const float* __restrict__ muc,
                                                  const float* __restrict__ var,
                                                  int* __restrict__ idxb,
                                                  float* __restrict__ slogb,
                                                  float* __restrict__ part) {
  const int tid = threadIdx.x, wid = tid >> 6, lane = tid & 63;

  if (blockIdx.x >= 64) {
    // ---------------- distill: (cos(mu,mu_clip)+1)/2 summed ----------------
    // All 16 loads (4 row-pairs) issued up-front: 16 KB in flight per wave,
    // then 4 independent reduction chains. Same rows / same per-row FMA and
    // DPP order as before -> bit-identical partials.
    __shared__ float s_red[4];
    const int blk = blockIdx.x - 64;
    const float* pmu = mu + (size_t)(blk * 4 + wid) * DD + lane * 4;
    const float* pmc = muc + (size_t)(blk * 4 + wid) * DD + lane * 4;
    float4 x[8], y[8];
#pragma unroll
    for (int j = 0; j < 4; j++) {  // rows r, r+8192, r+16384, r+24576
      const size_t off = (size_t)j * 8192 * DD;
      x[2 * j]     = *(const float4*)(pmu + off);
      x[2 * j + 1] = *(const float4*)(pmu + off + 256);
      y[2 * j]     = *(const float4*)(pmc + off);
      y[2 * j + 1] = *(const float4*)(pmc + off + 256);
    }
    float wacc = 0.f;
#pragma unroll
    for (int j = 0; j < 4; j++) {
      const float4 cxa = x[2 * j], cxb = x[2 * j + 1];
      const float4 cya = y[2 * j], cyb = y[2 * j + 1];
      float dot = 0.f, n1 = 0.f, n2 = 0.f;
      dot = fmaf(cxa.x, cya.x, fmaf(cxa.y, cya.y, fmaf(cxa.z, cya.z, fmaf(cxa.w, cya.w, dot))));
      n1 = fmaf(cxa.x, cxa.x, fmaf(cxa.y, cxa.y, fmaf(cxa.z, cxa.z, fmaf(cxa.w, cxa.w, n1))));
      n2 = fmaf(cya.x, cya.x, fmaf(cya.y, cya.y, fmaf(cya.z, cya.z, fmaf(cya.w, cya.w, n2))));
      dot = fmaf(cxb.x, cyb.x, fmaf(cxb.y, cyb.y, fmaf(cxb.z, cyb.z, fmaf(cxb.w, cyb.w, dot))));
      n1 = fmaf(cxb.x, cxb.x, fmaf(cxb.y, cxb.y, fmaf(cxb.z, cxb.z, fmaf(cxb.w, cxb.w, n1))));
      n2 = fmaf(cyb.x, cyb.x, fmaf(cyb.y, cyb.y, fmaf(cyb.z, cyb.z, fmaf(cyb.w, cyb.w, n2))));
      dot = wsum63(dot);
      n1 = wsum63(n1);
      n2 = wsum63(n2);
      if (lane == 63) {
        const float sim = dot / (fmaxf(sqrtf(n1), 1e-12f) * fmaxf(sqrtf(n2), 1e-12f));
        wacc += (sim + 1.0f) * 0.5f;
      }
    }
    if (lane == 63) s_red[wid] = wacc;
    __syncthreads();
    if (tid == 0) part[blk] = s_red[0] + s_red[1] + s_red[2] + s_red[3];
    return;
  }

  // ---------------- selection: sel 0: top-40 a*drop; 1: top-40 (max-a)*drop;
  //                  2: top-20 a*inner; 3: top-20 a*outer ----------------
  __shared__ float s_a[TT];
  __shared__ float s_v[TT];
  __shared__ __align__(16) unsigned s_hist[256];
  __shared__ unsigned s_state[2];
  __shared__ float s_bc[4];
  __shared__ unsigned s_bcu[4];
  __shared__ int s_idx[KEASY];

  const int b = blockIdx.x >> 2, sel = blockIdx.x & 3;
  for (int i = tid; i < TT; i += 256) s_a[i] = attn[b * TT + i];
  __syncthreads();

  float med = 0.f, mx = 0.f;
  if (sel == 1) {
    float lm = 0.f;
    for (int i = tid; i < TT; i += 256) lm = fmaxf(lm, s_a[i]);
    lm = wmax63(lm);
    if (lane == 63) s_bc[wid] = lm;
    __syncthreads();
    mx = fmaxf(fmaxf(s_bc[0], s_bc[1]), fmaxf(s_bc[2], s_bc[3]));
  } else if (sel >= 2) {
    // median = mean of 1024th/1025th largest (exact order statistics)
    const float v1 = radix_kth(s_a, 1024u, s_hist, s_state, tid);
    unsigned c = 0;
    float m2 = 0.f;
    for (int i = tid; i < TT; i += 256) {
      const float x = s_a[i];
      c += (x >= v1) ? 1u : 0u;
      m2 = (x < v1) ? fmaxf(m2, x) : m2;
    }
    c = wscanu(c);   // lane 63 = wave total
    m2 = wmax63(m2);
    if (lane == 63) { s_bc[wid] = m2; s_bcu[wid] = c; }
    __syncthreads();
    const unsigned ctot = s_bcu[0] + s_bcu[1] + s_bcu[2] + s_bcu[3];
    const float m2t = fmaxf(fmaxf(s_bc[0], s_bc[1]), fmaxf(s_bc[2], s_bc[3]));
    const float v2 = (ctot >= 1025u) ? v1 : m2t;  // 1025th largest
    med = 0.5f * (v1 + v2);
  }

  // scores -> s_v (all 256 threads)
  for (int i = tid; i < TT; i += 256) {
    const float a = s_a[i];
    float score;
    if (sel == 0) {
      score = a * drop[b * TT + i];
    } else if (sel == 1) {
      score = (mx - a) * drop[b * TT + i];
    } else {
      bool sall = true, ball = true, sany = false, bany = false;
#pragma unroll
      for (int o = -3; o <= 3; o++) {
        const int t = i + o;
        const bool one = (t >= 0 && t < TT) ? (s_a[t] > med) : false;  // 0-pad
        if (o >= -1 && o <= 1) { sall = sall && one; sany = sany || one; }
        ball = ball && one;
        bany = bany || one;
      }
      score = (sel == 2) ? ((sall && !ball) ? a : 0.f)    // er3 && !er7
                         : ((bany && !sany) ? a : 0.f);   // dl7 && !dl3
    }
    s_v[i] = score;
  }
  // radix_kth's internal first barrier orders these writes before any reads.
  const unsigned K = (sel < 2) ? KEASY : KHARD;
  const float thr = radix_kth(s_v, K, s_hist, s_state, tid);

  if (tid < 64) {  // wave 0: stable top-k extraction
    float v[32];
#pragma unroll
    for (int r = 0; r < 32; r++) v[r] = s_v[r * 64 + lane];
    // JAX stable top-k set: all (score > thr) plus the (K - c_gt) smallest-
    // index elements with score == thr.
    unsigned cgt = 0;
#pragma unroll
    for (int r = 0; r < 32; r++) cgt += (unsigned)__popcll(__ballot(v[r] > thr));
    unsigned need = (cgt < K) ? (K - cgt) : 0u;  // clamp: no underflow
    unsigned base = 0;
    const u64 lmask = (1ull << lane) - 1;
    int* dst = idxb + sel * (BB * KEASY) + b * KEASY;
#pragma unroll
    for (int r = 0; r < 32; r++) {
      const bool gt = v[r] > thr;
      const bool eq = v[r] == thr;
      const u64 beq = __ballot(eq);
      const unsigned neq = (unsigned)__popcll(beq);
      const unsigned take = (need < neq) ? need : neq;
      const bool tk = eq && ((unsigned)__popcll(beq & lmask) < take);
      const u64 bsel = __ballot(gt || tk);
      if (gt || tk) {
        const unsigned pos = base + (unsigned)__popcll(bsel & lmask);
        if (pos < K) {  // bounds guard
          dst[pos] = r * 64 + lane;
          s_idx[pos] = r * 64 + lane;
        }
      }
      base += (unsigned)__popcll(bsel);
      need -= take;
    }
  }
  __syncthreads();

  // slog for this block's selected rows: sum_d log(var+eps), 4 waves
  const int Ksel = (sel < 2) ? KEASY : KHARD;
  for (int j = wid; j < Ksel; j += 4) {
    const int t = s_idx[j];
    const float* row = var + ((size_t)b * TT + t) * DD;
    float a2 = 0.f;
#pragma unroll
    for (int c = 0; c < 2; c++) {
      float4 vv = *(const float4*)(row + c * 256 + lane * 4);
      a2 += __logf(vv.x + EPSF) + __logf(vv.y + EPSF) +
            __logf(vv.z + EPSF) + __logf(vv.w + EPSF);
    }
    a2 = wsum63(a2);
    if (lane == 63) slogb[sel * 640 + b * 40 + j] = a2;
  }
}

// =======================================================================
// k2: blocks [0,256) = KL for (b=blk>>4, klid=(blk>>2)&3, qchunk=blk&3);
// block 256 = distill partial reduce; block 257 = ortho.
// KL uses the 2-dot form:
//   dist(p,q) = 0.5*dot(mp^2+cvp, r) - dot(mp, mq*r)
//             + [0.5*dot(mq^2, r) + 0.5*slogq] - 0.5*slogp - 256
// with r = 1/(vq+eps). All 20 p-rows staged once in LDS (80 KB); each block
// handles 10 of the 40 q-rows; ONE DPP reduce per (p,q) pair.
// klid0: p=hard_act(2) q=easy_act(0); klid1: p=hard_act q=easy_bkg(1)
// klid2: p=hard_bkg(3) q=easy_bkg;    klid3: p=hard_bkg q=easy_act
// =======================================================================
__global__ __launch_bounds__(256, 1) void k_part2(const float* __restrict__ mu,
                                                  const float* __restrict__ var,
                                                  const int* __restrict__ idxb,
                                                  const float* __restrict__ slogb,
                                                  const float* __restrict__ part,
                                                  const float* __restrict__ text,
                                                  double* __restrict__ acc) {
  __shared__ __align__(16) float smem[2 * KHARD * DD];  // 80 KB
  const int tid = threadIdx.x, wid = tid >> 6, lane = tid & 63;
  const int blk = blockIdx.x;

  if (blk < 256) {
    const int b = blk >> 4, klid = (blk >> 2) & 3, qc = blk & 3;
    const int psel = (klid < 2) ? 2 : 3;
    const int qsel = (klid == 0 || klid == 3) ? 0 : 1;
    float* sP1 = smem;               // [20][512] mp^2 + cvp
    float* sP2 = smem + KHARD * DD;  // [20][512] mp
    __shared__ float sSlogP[KHARD];
    __shared__ float s_out[4];
    if (tid < KHARD) sSlogP[tid] = slogb[psel * 640 + b * 40 + tid];
    for (int i = tid; i < KHARD * 128; i += 256) {
      const int p = i >> 7, c = (i & 127) * 4;
      const int t = idxb[psel * 640 + b * 40 + p];
      const size_t base = ((size_t)b * TT + t) * DD + c;
      const float4 m = *(const float4*)(mu + base);
      const float4 vv = *(const float4*)(var + base);
      float4 p1;
      p1.x = fmaf(m.x, m.x, vv.x + EPSF);
      p1.y = fmaf(m.y, m.y, vv.y + EPSF);
      p1.z = fmaf(m.z, m.z, vv.z + EPSF);
      p1.w = fmaf(m.w, m.w, vv.w + EPSF);
      *(float4*)(sP1 + p * DD + c) = p1;
      *(float4*)(sP2 + p * DD + c) = m;
    }
    __syncthreads();

    const int d0 = lane * 4, d1 = 256 + lane * 4;
    const int qbase_i = qsel * 640 + b * 40 + qc * 10;
    float wacc = 0.f;
#pragma unroll 1
    for (int j = wid; j < 10; j += 4) {  // waves 0,1: 3 q's; waves 2,3: 2 q's
      const int qidx = idxb[qbase_i + j];
      const float cslq = slogb[qbase_i + j];
      const float* qm = mu + ((size_t)b * TT + qidx) * DD;
      const float* qv = var + ((size_t)b * TT + qidx) * DD;
      const float4 cma = *(const float4*)(qm + d0);
      const float4 cmb = *(const float4*)(qm + d1);
      const float4 cva = *(const float4*)(qv + d0);
      const float4 cvb = *(const float4*)(qv + d1);
      float4 ra, rb, qra, qrb;
      ra.x = 1.0f / (cva.x + EPSF); ra.y = 1.0f / (cva.y + EPSF);
      ra.z = 1.0f / (cva.z + EPSF); ra.w = 1.0f / (cva.w + EPSF);
      rb.x = 1.0f / (cvb.x + EPSF); rb.y = 1.0f / (cvb.y + EPSF);
      rb.z = 1.0f / (cvb.z + EPSF); rb.w = 1.0f / (cvb.w + EPSF);
      qra.x = cma.x * ra.x; qra.y = cma.y * ra.y;
      qra.z = cma.z * ra.z; qra.w = cma.w * ra.w;
      qrb.x = cmb.x * rb.x; qrb.y = cmb.y * rb.y;
      qrb.z = cmb.z * rb.z; qrb.w = cmb.w * rb.w;
      float cqp = cma.x * qra.x + cma.y * qra.y + cma.z * qra.z + cma.w * qra.w +
                  cmb.x * qrb.x + cmb.y * qrb.y + cmb.z * qrb.z + cmb.w * qrb.w;
      const float cq = wsum63(cqp);  // valid in lane 63 only
      for (int p = 0; p < KHARD; p++) {
        const float4 p1a = *(const float4*)(sP1 + p * DD + d0);
        const float4 p1b = *(const float4*)(sP1 + p * DD + d1);
        const float4 p2a = *(const float4*)(sP2 + p * DD + d0);
        const float4 p2b = *(const float4*)(sP2 + p * DD + d1);
        const float s1 = p1a.x * ra.x + p1a.y * ra.y + p1a.z * ra.z + p1a.w * ra.w +
                         p1b.x * rb.x + p1b.y * rb.y + p1b.z * rb.z + p1b.w * rb.w;
        const float s2 = p2a.x * qra.x + p2a.y * qra.y + p2a.z * qra.z + p2a.w * qra.w +
                         p2b.x * qrb.x + p2b.y * qrb.y + p2b.z * qrb.z + p2b.w * qrb.w;
        const float h = wsum63(fmaf(0.5f, s1, -s2));
        if (lane == 63) {
          const float dist = h + 0.5f * cq + 0.5f * cslq - 0.5f * sSlogP[p] - 256.0f;
          wacc += 1.0f / (dist + 1.0f);
        }
      }
    }
    if (lane == 63) s_out[wid] = wacc;
    __syncthreads();
    if (tid == 0)
      acc[blk] = (double)s_out[0] + s_out[1] + s_out[2] + s_out[3];
    return;
  }

  if (blk == 256) {  // distill partial reduce -> acc[256]
    double* sd = (double*)smem;
    double s = 0.0;
    for (int i = tid; i < 2048; i += 256) s += (double)part[i];
    sd[tid] = s;
    __syncthreads();
    for (int st = 128; st; st >>= 1) {
      if (tid < st) sd[tid] += sd[tid + st];
      __syncthreads();
    }
    if (tid == 0) acc[256] = sd[0];
    return;
  }

  // blk == 257: ortho = ||normalize(text) @ normalize(text)^T - I||_F -> acc[257]
  {
    float* s_e = smem;  // CC*DD = 40 KB
    __shared__ float s_red4[4];
    for (int r = wid; r < CC; r += 4) {
      float4 v[2];
      float ss = 0.f;
#pragma unroll
      for (int c = 0; c < 2; c++) {
        v[c] = *(const float4*)(text + r * DD + c * 256 + lane * 4);
        ss += v[c].x * v[c].x + v[c].y * v[c].y + v[c].z * v[c].z + v[c].w * v[c].w;
      }
      ss = wsum_bc(ss);
      const float n = fmaxf(sqrtf(ss), 1e-12f);
#pragma unroll
      for (int c = 0; c < 2; c++) {
        float4 w = v[c];
        w.x /= n; w.y /= n; w.z /= n; w.w /= n;
        *(float4*)(s_e + r * DD + c * 256 + lane * 4) = w;
      }
    }
    __syncthreads();
    float wss = 0.f;
    for (int p = wid; p < CC * CC; p += 4) {
      const int i = p / CC, j = p % CC;
      float dot = 0.f;
#pragma unroll
      for (int c = 0; c < 2; c++) {
        const int d0 = c * 256 + lane * 4;
        const float4 x = *(const float4*)(s_e + i * DD + d0);
        const float4 y = *(const float4*)(s_e + j * DD + d0);
        dot += x.x * y.x + x.y * y.y + x.z * y.z + x.w * y.w;
      }
      dot = wsum63(dot);
      if (lane == 63) {
        const float s = dot - (i == j ? 1.0f : 0.0f);
        wss += s * s;
      }
    }
    if (lane == 63) s_red4[wid] = wss;
    __syncthreads();
    if (tid == 0)
      acc[257] = (double)(s_red4[0] + s_red4[1] + s_red4[2] + s_red4[3]);
  }
}

// =======================================================================
// k3: tiny epilogue (1 block, 64 threads)
// =======================================================================
__global__ __launch_bounds__(64) void k_final(const double* __restrict__ acc,
                                              float* __restrict__ out) {
  __shared__ double sla[16], slb[16];
  const int tid = threadIdx.x;
  if (tid < 16) {
    const double* ab = acc + tid * 16;  // [klid*4 + qc] for this b
    const double pa = (ab[0] + ab[1] + ab[2] + ab[3]) / 800.0;
    const double na = (ab[4] + ab[5] + ab[6] + ab[7]) / 800.0;
    const double pb = (ab[8] + ab[9] + ab[10] + ab[11]) / 800.0;
    const double nb = (ab[12] + ab[13] + ab[14] + ab[15]) / 800.0;
    sla[tid] = -(log(pa) + log(1.0 - na));
    slb[tid] = -(log(pb) + log(1.0 - nb));
  }
  __syncthreads();
  if (tid == 0) {
    double act = 0.0, bkg = 0.0;
    for (int b = 0; b < 16; b++) { act += sla[b]; bkg += slb[b]; }
    act /= 16.0;
    bkg /= 16.0;
    const double distill = -log(acc[256] / (double)(BB * TT));
    const double ortho = sqrt(acc[257]);
    const double total = distill + act + bkg + ortho;
    out[0] = (float)total;
    out[1] = (float)distill;
    out[2] = (float)act;
    out[3] = (float)bkg;
    out[4] = (float)ortho;
  }
}

extern "C" void kernel_launch(void* const* d_in, const int* in_sizes, int n_in,
                              void* d_out, int out_size, void* d_ws, size_t ws_size,
                              hipStream_t stream) {
  const float* attn = (const float*)d_in[0];
  const float* mu   = (const float*)d_in[1];
  const float* var  = (const float*)d_in[2];
  const float* muc  = (const float*)d_in[3];
  const float* text = (const float*)d_in[4];
  const float* drop = (const float*)d_in[5];
  float* out = (float*)d_out;

  // workspace layout (~31 KB). Every acc slot [0..257] is overwritten by
  // k_part2 (no zeroing needed despite per-call ws poisoning).
  double* acc  = (double*)d_ws;           // 258: [0..255] kl (b*16+klid*4+qc), [256] distill, [257] ortho
  int* idxb    = (int*)(acc + 258);       // 4*16*40 ints
  float* slogb = (float*)(idxb + 2560);   // 4*16*40 f32
  float* part  = (float*)(slogb + 2560);  // 2048 f32 distill partials

  k_main1<<<2112, 256, 0, stream>>>(attn, drop, mu, muc, var, idxb, slogb, part);
  k_part2<<<258, 256, 0, stream>>>(mu, var, idxb, slogb, part, text, acc);
  k_final<<<1, 64, 0, stream>>>(acc, out);
}

// Round 4
// 235.879 us; speedup vs baseline: 1.0215x; 1.0215x over previous
//
#include <hip/hip_runtime.h>
#include <math.h>

// ProbLoss: B=16, T=2048, D=512, C=20. Inputs (f32):
//   d_in[0] attn [B,T,1], d_in[1] mu [B,T,D], d_in[2] var [B,T,D],
//   d_in[3] mu_clip [B,T,D], d_in[4] text_feat [C,D], d_in[5] drop_mask [B,T]
// Output: 5 f32 scalars (total, distill, act_loss, bkg_loss, ortho).

#define BB 16
#define TT 2048
#define DD 512
#define CC 20
#define KEASY 40
#define KHARD 20
#define EPSF 1e-5f

typedef unsigned long long u64;

// ---- DPP wave-64 reductions / scans (VALU-only) ----
template <int CTRL>
__device__ __forceinline__ float dpp_mov(float x) {
  return __int_as_float(__builtin_amdgcn_update_dpp(
      0, __float_as_int(x), CTRL, 0xF, 0xF, true));  // bound_ctrl: 0-fill
}
template <int CTRL, int RM>
__device__ __forceinline__ unsigned dpp_movu(unsigned x) {
  return (unsigned)__builtin_amdgcn_update_dpp(0, (int)x, CTRL, RM, 0xF, true);
}
__device__ __forceinline__ float wsum63(float v) {  // total valid in lane 63
  v += dpp_mov<0x111>(v);
  v += dpp_mov<0x112>(v);
  v += dpp_mov<0x114>(v);
  v += dpp_mov<0x118>(v);
  v += dpp_mov<0x142>(v);
  v += dpp_mov<0x143>(v);
  return v;
}
__device__ __forceinline__ float wsum_bc(float v) {  // broadcast to all lanes
  return __int_as_float(__builtin_amdgcn_readlane(__float_as_int(wsum63(v)), 63));
}
__device__ __forceinline__ float wmax63(float v) {  // nonneg values; max in lane 63
  v = fmaxf(v, dpp_mov<0x111>(v));
  v = fmaxf(v, dpp_mov<0x112>(v));
  v = fmaxf(v, dpp_mov<0x114>(v));
  v = fmaxf(v, dpp_mov<0x118>(v));
  v = fmaxf(v, dpp_mov<0x142>(v));
  v = fmaxf(v, dpp_mov<0x143>(v));
  return v;
}
// Wave-64 inclusive prefix scan: row_bcast:15 needs row_mask=0xa and
// row_bcast:31 needs row_mask=0xc (canonical GCN scan).
__device__ __forceinline__ unsigned wscanu(unsigned v) {
  v += dpp_movu<0x111, 0xF>(v);
  v += dpp_movu<0x112, 0xF>(v);
  v += dpp_movu<0x114, 0xF>(v);
  v += dpp_movu<0x118, 0xF>(v);
  v += dpp_movu<0x142, 0xa>(v);  // row1 += lane15; row3 += lane47
  v += dpp_movu<0x143, 0xc>(v);  // rows 2,3 += lane31 (now sum[0..31])
  return v;
}

// k-th largest VALUE (with multiplicity) among the TT nonneg floats in LDS sbuf.
// Block-parallel radix select: 4 passes of 8-bit histogram + wave0 DPP scan.
// s_hist4 = 4 per-wave copies of 256 bins: each wave atomics into its own copy
// (hot-bin same-address serialization / 4, zero inter-wave conflicts); the
// pick phase sums the 4 copies -- integer counts, so the threshold stays
// bit-exact (IEEE nonneg float order == uint order).
__device__ __forceinline__ float radix_kth(const float* sbuf, unsigned k,
                                           unsigned* s_hist4, unsigned* s_state,
                                           int tid, int wid) {
#pragma unroll 1
  for (int round = 0; round < 4; ++round) {
    s_hist4[tid] = 0;
    s_hist4[256 + tid] = 0;
    s_hist4[512 + tid] = 0;
    s_hist4[768 + tid] = 0;
    if (round == 0 && tid == 0) { s_state[0] = 0u; s_state[1] = k; }
    __syncthreads();
    const int shift = 24 - 8 * round;
    const unsigned mask_hi = (round == 0) ? 0u : (0xFFFFFFFFu << (shift + 8));
    const unsigned pref = s_state[0];
    const unsigned kk = s_state[1];
    unsigned* myhist = s_hist4 + (wid << 8);
    // histogram, bin index DESCENDING in value; run-length pre-aggregation
    // caps same-bin LDS-atomic contention (score arrays are zero-heavy).
    unsigned curbin = 0xFFFFFFFFu, curc = 0;
    for (int i = tid; i < TT; i += 256) {
      const unsigned key = __float_as_uint(sbuf[i]);
      if ((key & mask_hi) == pref) {
        const unsigned bin = 255u - ((key >> shift) & 255u);
        if (bin == curbin) {
          curc++;
        } else {
          if (curc) atomicAdd(&myhist[curbin], curc);
          curbin = bin;
          curc = 1;
        }
      }
    }
    if (curc) atomicAdd(&myhist[curbin], curc);
    __syncthreads();
    if (tid < 64) {  // wave 0: pick the bin containing rank kk
      const uint4 h0 = *(const uint4*)(s_hist4 + 4 * tid);
      const uint4 h1 = *(const uint4*)(s_hist4 + 256 + 4 * tid);
      const uint4 h2 = *(const uint4*)(s_hist4 + 512 + 4 * tid);
      const uint4 h3 = *(const uint4*)(s_hist4 + 768 + 4 * tid);
      const unsigned b0 = h0.x + h1.x + h2.x + h3.x;
      const unsigned b1 = h0.y + h1.y + h2.y + h3.y;
      const unsigned b2 = h0.z + h1.z + h2.z + h3.z;
      const unsigned b3 = h0.w + h1.w + h2.w + h3.w;
      const unsigned s0 = b0, s1 = s0 + b1, s2 = s1 + b2, s3 = s2 + b3;
      const unsigned P = wscanu(s3);  // inclusive over lane totals
      const unsigned E = P - s3;      // exclusive
      const u64 bal = __ballot(P >= kk);
      const int L = (int)__ffsll(bal) - 1;  // first lane reaching kk
      if (tid == L) {
        unsigned binj, cb;
        if (E + s0 >= kk)      { binj = 0u; cb = E; }
        else if (E + s1 >= kk) { binj = 1u; cb = E + s0; }
        else if (E + s2 >= kk) { binj = 2u; cb = E + s1; }
        else                   { binj = 3u; cb = E + s2; }
        const unsigned digit = 255u - (4u * (unsigned)tid + binj);
        s_state[0] = pref | (digit << shift);
        s_state[1] = kk - cb;
      }
    }
    __syncthreads();
  }
  return __uint_as_float(s_state[0]);
}

// =======================================================================
// k_sel: 64 blocks, selection + slog ONLY. Runs alone (no co-residency with
// the BW-heavy distill waves that previously stretched its serial sections).
// sel 0: top-40 a*drop; 1: top-40 (max-a)*drop; 2: top-20 a*inner;
// 3: top-20 a*outer.
// =======================================================================
__global__ __launch_bounds__(256, 2) void k_sel(const float* __restrict__ attn,
                                                const float* __restrict__ drop,
                                                const float* __restrict__ var,
                                                int* __restrict__ idxb,
                                                float* __restrict__ slogb) {
  const int tid = threadIdx.x, wid = tid >> 6, lane = tid & 63;
  __shared__ float s_a[TT];
  __shared__ float s_v[TT];
  __shared__ __align__(16) unsigned s_hist4[1024];  // 4 per-wave copies
  __shared__ unsigned s_state[2];
  __shared__ float s_bc[4];
  __shared__ unsigned s_bcu[4];
  __shared__ int s_idx[KEASY];

  const int b = blockIdx.x >> 2, sel = blockIdx.x & 3;
  for (int i = tid; i < TT; i += 256) s_a[i] = attn[b * TT + i];
  __syncthreads();

  float med = 0.f, mx = 0.f;
  if (sel == 1) {
    float lm = 0.f;
    for (int i = tid; i < TT; i += 256) lm = fmaxf(lm, s_a[i]);
    lm = wmax63(lm);
    if (lane == 63) s_bc[wid] = lm;
    __syncthreads();
    mx = fmaxf(fmaxf(s_bc[0], s_bc[1]), fmaxf(s_bc[2], s_bc[3]));
  } else if (sel >= 2) {
    // median = mean of 1024th/1025th largest (exact order statistics)
    const float v1 = radix_kth(s_a, 1024u, s_hist4, s_state, tid, wid);
    unsigned c = 0;
    float m2 = 0.f;
    for (int i = tid; i < TT; i += 256) {
      const float x = s_a[i];
      c += (x >= v1) ? 1u : 0u;
      m2 = (x < v1) ? fmaxf(m2, x) : m2;
    }
    c = wscanu(c);   // lane 63 = wave total
    m2 = wmax63(m2);
    if (lane == 63) { s_bc[wid] = m2; s_bcu[wid] = c; }
    __syncthreads();
    const unsigned ctot = s_bcu[0] + s_bcu[1] + s_bcu[2] + s_bcu[3];
    const float m2t = fmaxf(fmaxf(s_bc[0], s_bc[1]), fmaxf(s_bc[2], s_bc[3]));
    const float v2 = (ctot >= 1025u) ? v1 : m2t;  // 1025th largest
    med = 0.5f * (v1 + v2);
  }

  // scores -> s_v (all 256 threads)
  for (int i = tid; i < TT; i += 256) {
    const float a = s_a[i];
    float score;
    if (sel == 0) {
      score = a * drop[b * TT + i];
    } else if (sel == 1) {
      score = (mx - a) * drop[b * TT + i];
    } else {
      bool sall = true, ball = true, sany = false, bany = false;
#pragma unroll
      for (int o = -3; o <= 3; o++) {
        const int t = i + o;
        const bool one = (t >= 0 && t < TT) ? (s_a[t] > med) : false;  // 0-pad
        if (o >= -1 && o <= 1) { sall = sall && one; sany = sany || one; }
        ball = ball && one;
        bany = bany || one;
      }
      score = (sel == 2) ? ((sall && !ball) ? a : 0.f)    // er3 && !er7
                         : ((bany && !sany) ? a : 0.f);   // dl7 && !dl3
    }
    s_v[i] = score;
  }
  // radix_kth's internal first barrier orders these writes before any reads.
  const unsigned K = (sel < 2) ? KEASY : KHARD;
  const float thr = radix_kth(s_v, K, s_hist4, s_state, tid, wid);

  if (tid < 64) {  // wave 0: stable top-k extraction
    float v[32];
#pragma unroll
    for (int r = 0; r < 32; r++) v[r] = s_v[r * 64 + lane];
    // JAX stable top-k set: all (score > thr) plus the (K - c_gt) smallest-
    // index elements with score == thr.
    unsigned cgt = 0;
#pragma unroll
    for (int r = 0; r < 32; r++) cgt += (unsigned)__popcll(__ballot(v[r] > thr));
    unsigned need = (cgt < K) ? (K - cgt) : 0u;  // clamp: no underflow
    unsigned base = 0;
    const u64 lmask = (1ull << lane) - 1;
    int* dst = idxb + sel * (BB * KEASY) + b * KEASY;
#pragma unroll
    for (int r = 0; r < 32; r++) {
      const bool gt = v[r] > thr;
      const bool eq = v[r] == thr;
      const u64 beq = __ballot(eq);
      const unsigned neq = (unsigned)__popcll(beq);
      const unsigned take = (need < neq) ? need : neq;
      const bool tk = eq && ((unsigned)__popcll(beq & lmask) < take);
      const u64 bsel = __ballot(gt || tk);
      if (gt || tk) {
        const unsigned pos = base + (unsigned)__popcll(bsel & lmask);
        if (pos < K) {  // bounds guard
          dst[pos] = r * 64 + lane;
          s_idx[pos] = r * 64 + lane;
        }
      }
      base += (unsigned)__popcll(bsel);
      need -= take;
    }
  }
  __syncthreads();

  // slog for this block's selected rows: sum_d log(var+eps), 4 waves
  const int Ksel = (sel < 2) ? KEASY : KHARD;
  for (int j = wid; j < Ksel; j += 4) {
    const int t = s_idx[j];
    const float* row = var + ((size_t)b * TT + t) * DD;
    float a2 = 0.f;
#pragma unroll
    for (int c = 0; c < 2; c++) {
      float4 vv = *(const float4*)(row + c * 256 + lane * 4);
      a2 += __logf(vv.x + EPSF) + __logf(vv.y + EPSF) +
            __logf(vv.z + EPSF) + __logf(vv.w + EPSF);
    }
    a2 = wsum63(a2);
    if (lane == 63) slogb[sel * 640 + b * 40 + j] = a2;
  }
}

// =======================================================================
// k_main2: fused post-selection kernel, 2305 blocks.
//   [0,256)   KL for (b=blk>>4, klid=(blk>>2)&3, qchunk=blk&3) -> acc[blk]
//   256       ortho -> acc[256]
//   [257,2305) distill partials (dblk = blk-257) -> part[dblk]
// Distill overlaps the KL/ortho work (they use different pipes: BW vs
// VALU/LDS); the distill partial-reduce moved to k_final to avoid a
// same-grid cross-block dependency.
// KL uses the 2-dot form:
//   dist(p,q) = 0.5*dot(mp^2+cvp, r) - dot(mp, mq*r)
//             + [0.5*dot(mq^2, r) + 0.5*slogq] - 0.5*slogp - 256
// with r = 1/(vq+eps). 20 p-rows staged in LDS (80 KB); 10 q-rows/block.
// klid0: p=hard_act(2) q=easy_act(0); klid1: p=hard_act q=easy_bkg(1)
// klid2: p=hard_bkg(3) q=easy_bkg;    klid3: p=hard_bkg q=easy_act
// =======================================================================
__global__ __launch_bounds__(256, 2) void k_main2(const float* __restrict__ mu,
                                                  const float* __restrict__ var,
                                                  const float* __restrict__ muc,
                                                  const int* __restrict__ idxb,
                                                  const float* __restrict__ slogb,
                                                  const float* __restrict__ text,
                                                  double* __restrict__ acc,
                                                  float* __restrict__ part) {
  __shared__ __align__(16) float smem[2 * KHARD * DD];  // 80 KB
  const int tid = threadIdx.x, wid = tid >> 6, lane = tid & 63;
  const int blk = blockIdx.x;

  if (blk >= 257) {
    // ---------------- distill: (cos(mu,mu_clip)+1)/2 summed ----------------
    float* s_red = smem;
    const int dblk = blk - 257;
    const float* pmu = mu + (size_t)(dblk * 4 + wid) * DD + lane * 4;
    const float* pmc = muc + (size_t)(dblk * 4 + wid) * DD + lane * 4;
    float4 x[8], y[8];
#pragma unroll
    for (int j = 0; j < 4; j++) {  // rows r, r+8192, r+16384, r+24576
      const size_t off = (size_t)j * 8192 * DD;
      x[2 * j]     = *(const float4*)(pmu + off);
      x[2 * j + 1] = *(const float4*)(pmu + off + 256);
      y[2 * j]     = *(const float4*)(pmc + off);
      y[2 * j + 1] = *(const float4*)(pmc + off + 256);
    }
    float wacc = 0.f;
#pragma unroll
    for (int j = 0; j < 4; j++) {
      const float4 cxa = x[2 * j], cxb = x[2 * j + 1];
      const float4 cya = y[2 * j], cyb = y[2 * j + 1];
      float dot = 0.f, n1 = 0.f, n2 = 0.f;
      dot = fmaf(cxa.x, cya.x, fmaf(cxa.y, cya.y, fmaf(cxa.z, cya.z, fmaf(cxa.w, cya.w, dot))));
      n1 = fmaf(cxa.x, cxa.x, fmaf(cxa.y, cxa.y, fmaf(cxa.z, cxa.z, fmaf(cxa.w, cxa.w, n1))));
      n2 = fmaf(cya.x, cya.x, fmaf(cya.y, cya.y, fmaf(cya.z, cya.z, fmaf(cya.w, cya.w, n2))));
      dot = fmaf(cxb.x, cyb.x, fmaf(cxb.y, cyb.y, fmaf(cxb.z, cyb.z, fmaf(cxb.w, cyb.w, dot))));
      n1 = fmaf(cxb.x, cxb.x, fmaf(cxb.y, cxb.y, fmaf(cxb.z, cxb.z, fmaf(cxb.w, cxb.w, n1))));
      n2 = fmaf(cyb.x, cyb.x, fmaf(cyb.y, cyb.y, fmaf(cyb.z, cyb.z, fmaf(cyb.w, cyb.w, n2))));
      dot = wsum63(dot);
      n1 = wsum63(n1);
      n2 = wsum63(n2);
      if (lane == 63) {
        const float sim = dot / (fmaxf(sqrtf(n1), 1e-12f) * fmaxf(sqrtf(n2), 1e-12f));
        wacc += (sim + 1.0f) * 0.5f;
      }
    }
    if (lane == 63) s_red[wid] = wacc;
    __syncthreads();
    if (tid == 0) part[dblk] = s_red[0] + s_red[1] + s_red[2] + s_red[3];
    return;
  }

  if (blk < 256) {
    const int b = blk >> 4, klid = (blk >> 2) & 3, qc = blk & 3;
    const int psel = (klid < 2) ? 2 : 3;
    const int qsel = (klid == 0 || klid == 3) ? 0 : 1;
    float* sP1 = smem;               // [20][512] mp^2 + cvp
    float* sP2 = smem + KHARD * DD;  // [20][512] mp
    __shared__ float sSlogP[KHARD];
    __shared__ float s_out[4];
    if (tid < KHARD) sSlogP[tid] = slogb[psel * 640 + b * 40 + tid];
    for (int i = tid; i < KHARD * 128; i += 256) {
      const int p = i >> 7, c = (i & 127) * 4;
      const int t = idxb[psel * 640 + b * 40 + p];
      const size_t base = ((size_t)b * TT + t) * DD + c;
      const float4 m = *(const float4*)(mu + base);
      const float4 vv = *(const float4*)(var + base);
      float4 p1;
      p1.x = fmaf(m.x, m.x, vv.x + EPSF);
      p1.y = fmaf(m.y, m.y, vv.y + EPSF);
      p1.z = fmaf(m.z, m.z, vv.z + EPSF);
      p1.w = fmaf(m.w, m.w, vv.w + EPSF);
      *(float4*)(sP1 + p * DD + c) = p1;
      *(float4*)(sP2 + p * DD + c) = m;
    }
    __syncthreads();

    const int d0 = lane * 4, d1 = 256 + lane * 4;
    const int qbase_i = qsel * 640 + b * 40 + qc * 10;
    float wacc = 0.f;
#pragma unroll 1
    for (int j = wid; j < 10; j += 4) {  // waves 0,1: 3 q's; waves 2,3: 2 q's
      const int qidx = idxb[qbase_i + j];
      const float cslq = slogb[qbase_i + j];
      const float* qm = mu + ((size_t)b * TT + qidx) * DD;
      const float* qv = var + ((size_t)b * TT + qidx) * DD;
      const float4 cma = *(const float4*)(qm + d0);
      const float4 cmb = *(const float4*)(qm + d1);
      const float4 cva = *(const float4*)(qv + d0);
      const float4 cvb = *(const float4*)(qv + d1);
      float4 ra, rb, qra, qrb;
      ra.x = 1.0f / (cva.x + EPSF); ra.y = 1.0f / (cva.y + EPSF);
      ra.z = 1.0f / (cva.z + EPSF); ra.w = 1.0f / (cva.w + EPSF);
      rb.x = 1.0f / (cvb.x + EPSF); rb.y = 1.0f / (cvb.y + EPSF);
      rb.z = 1.0f / (cvb.z + EPSF); rb.w = 1.0f / (cvb.w + EPSF);
      qra.x = cma.x * ra.x; qra.y = cma.y * ra.y;
      qra.z = cma.z * ra.z; qra.w = cma.w * ra.w;
      qrb.x = cmb.x * rb.x; qrb.y = cmb.y * rb.y;
      qrb.z = cmb.z * rb.z; qrb.w = cmb.w * rb.w;
      float cqp = cma.x * qra.x + cma.y * qra.y + cma.z * qra.z + cma.w * qra.w +
                  cmb.x * qrb.x + cmb.y * qrb.y + cmb.z * qrb.z + cmb.w * qrb.w;
      const float cq = wsum63(cqp);  // valid in lane 63 only
      for (int p = 0; p < KHARD; p++) {
        const float4 p1a = *(const float4*)(sP1 + p * DD + d0);
        const float4 p1b = *(const float4*)(sP1 + p * DD + d1);
        const float4 p2a = *(const float4*)(sP2 + p * DD + d0);
        const float4 p2b = *(const float4*)(sP2 + p * DD + d1);
        const float s1 = p1a.x * ra.x + p1a.y * ra.y + p1a.z * ra.z + p1a.w * ra.w +
                         p1b.x * rb.x + p1b.y * rb.y + p1b.z * rb.z + p1b.w * rb.w;
        const float s2 = p2a.x * qra.x + p2a.y * qra.y + p2a.z * qra.z + p2a.w * qra.w +
                         p2b.x * qrb.x + p2b.y * qrb.y + p2b.z * qrb.z + p2b.w * qrb.w;
        const float h = wsum63(fmaf(0.5f, s1, -s2));
        if (lane == 63) {
          const float dist = h + 0.5f * cq + 0.5f * cslq - 0.5f * sSlogP[p] - 256.0f;
          wacc += 1.0f / (dist + 1.0f);
        }
      }
    }
    if (lane == 63) s_out[wid] = wacc;
    __syncthreads();
    if (tid == 0)
      acc[blk] = (double)s_out[0] + s_out[1] + s_out[2] + s_out[3];
    return;
  }

  // blk == 256: ortho = ||normalize(text) @ normalize(text)^T - I||_F -> acc[256]
  {
    float* s_e = smem;  // CC*DD = 40 KB
    __shared__ float s_red4[4];
    for (int r = wid; r < CC; r += 4) {
      float4 v[2];
      float ss = 0.f;
#pragma unroll
      for (int c = 0; c < 2; c++) {
        v[c] = *(const float4*)(text + r * DD + c * 256 + lane * 4);
        ss += v[c].x * v[c].x + v[c].y * v[c].y + v[c].z * v[c].z + v[c].w * v[c].w;
      }
      ss = wsum_bc(ss);
      const float n = fmaxf(sqrtf(ss), 1e-12f);
#pragma unroll
      for (int c = 0; c < 2; c++) {
        float4 w = v[c];
        w.x /= n; w.y /= n; w.z /= n; w.w /= n;
        *(float4*)(s_e + r * DD + c * 256 + lane * 4) = w;
      }
    }
    __syncthreads();
    float wss = 0.f;
    for (int p = wid; p < CC * CC; p += 4) {
      const int i = p / CC, j = p % CC;
      float dot = 0.f;
#pragma unroll
      for (int c = 0; c < 2; c++) {
        const int d0 = c * 256 + lane * 4;
        const float4 x = *(const float4*)(s_e + i * DD + d0);
        const float4 y = *(const float4*)(s_e + j * DD + d0);
        dot += x.x * y.x + x.y * y.y + x.z * y.z + x.w * y.w;
      }
      dot = wsum63(dot);
      if (lane == 63) {
        const float s = dot - (i == j ? 1.0f : 0.0f);
        wss += s * s;
      }
    }
    if (lane == 63) s_red4[wid] = wss;
    __syncthreads();
    if (tid == 0)
      acc[256] = (double)(s_red4[0] + s_red4[1] + s_red4[2] + s_red4[3]);
  }
}

// =======================================================================
// k_final: 1 block, 256 threads. Distill partial reduce + epilogue.
// =======================================================================
__global__ __launch_bounds__(256) void k_final(const double* __restrict__ acc,
                                               const float* __restrict__ part,
                                               float* __restrict__ out) {
  __shared__ double sd[256];
  __shared__ double sla[16], slb[16];
  const int tid = threadIdx.x;
  double s = 0.0;
  for (int i = tid; i < 2048; i += 256) s += (double)part[i];
  sd[tid] = s;
  __syncthreads();
  for (int st = 128; st; st >>= 1) {
    if (tid < st) sd[tid] += sd[tid + st];
    __syncthreads();
  }
  if (tid < 16) {
    const double* ab = acc + tid * 16;  // [klid*4 + qc] for this b
    const double pa = (ab[0] + ab[1] + ab[2] + ab[3]) / 800.0;
    const double na = (ab[4] + ab[5] + ab[6] + ab[7]) / 800.0;
    const double pb = (ab[8] + ab[9] + ab[10] + ab[11]) / 800.0;
    const double nb = (ab[12] + ab[13] + ab[14] + ab[15]) / 800.0;
    sla[tid] = -(log(pa) + log(1.0 - na));
    slb[tid] = -(log(pb) + log(1.0 - nb));
  }
  __syncthreads();
  if (tid == 0) {
    double act = 0.0, bkg = 0.0;
    for (int b = 0; b < 16; b++) { act += sla[b]; bkg += slb[b]; }
    act /= 16.0;
    bkg /= 16.0;
    const double distill = -log(sd[0] / (double)(BB * TT));
    const double ortho = sqrt(acc[256]);
    const double total = distill + act + bkg + ortho;
    out[0] = (float)total;
    out[1] = (float)distill;
    out[2] = (float)act;
    out[3] = (float)bkg;
    out[4] = (float)ortho;
  }
}

extern "C" void kernel_launch(void* const* d_in, const int* in_sizes, int n_in,
                              void* d_out, int out_size, void* d_ws, size_t ws_size,
                              hipStream_t stream) {
  const float* attn = (const float*)d_in[0];
  const float* mu   = (const float*)d_in[1];
  const float* var  = (const float*)d_in[2];
  const float* muc  = (const float*)d_in[3];
  const float* text = (const float*)d_in[4];
  const float* drop = (const float*)d_in[5];
  float* out = (float*)d_out;

  // workspace layout (~31 KB). Every consumed slot is overwritten each call
  // (no zeroing needed despite per-call ws poisoning): acc[0..255] KL,
  // acc[256] ortho by k_main2; part[0..2047] by k_main2 distill blocks.
  double* acc  = (double*)d_ws;           // 257 doubles
  int* idxb    = (int*)(acc + 257);       // 4*16*40 ints
  float* slogb = (float*)(idxb + 2560);   // 4*16*40 f32
  float* part  = (float*)(slogb + 2560);  // 2048 f32 distill partials

  k_sel<<<64, 256, 0, stream>>>(attn, drop, var, idxb, slogb);
  k_main2<<<2305, 256, 0, stream>>>(mu, var, muc, idxb, slogb, text, acc, part);
  k_final<<<1, 256, 0, stream>>>(acc, part, out);
}